// Round 14
// baseline (994.638 us; speedup 1.0000x reference)
//
#include <hip/hip_runtime.h>
#include <math.h>

// Problem constants
#define E_N   128
#define L_N   16
#define PE_N  33
#define F_N   256
#define W_N   512
#define HOP_N 256
#define C_N   257
#define H_N   512
#define GP_N  128
#define F2_N  512
#define NSAMP (F_N*HOP_N)     // 65536
#define M_ROWS (E_N*F_N)      // 32768
#define KLD   544             // bf16 leading dim for iDFT operands (17*32)
#define MDLD  544             // fp32 m/d interleaved buffer leading dim
#define WMD_N 768             // padded interleaved mag/dith weight rows (3*256)
#define KC    16              // k-chunk per phase block

#define BM 256
#define BN 256

typedef float f32x4 __attribute__((ext_vector_type(4)));
typedef short s16x8 __attribute__((ext_vector_type(8)));

__device__ __forceinline__ float selu_f(float x){
    const float alpha = 1.6732632423543772f;
    const float scale = 1.0507009873554805f;
    return scale * (x > 0.f ? x : alpha * expm1f(x));
}
__device__ __forceinline__ unsigned short f2bf(float x){
    unsigned u = __float_as_uint(x);
    return (unsigned short)((u + 0x7fffu + ((u >> 16) & 1u)) >> 16);
}
__device__ __forceinline__ float bf2f(unsigned short h){
    return __uint_as_float((unsigned)h << 16);
}
__device__ __forceinline__ void split2(float x, unsigned short* h, unsigned short* l){
    unsigned short hh = f2bf(x);
    *h = hh;
    *l = f2bf(x - bf2f(hh));
}

// ---------------- MFMA GEMM: C = A(MxK) @ B(NxK)^T via split-bf16 ----------
// 256x256 tile, R8's VERIFIED pipeline (dbuf LDS + counted vmcnt(8) + raw
// barriers) at halved staging-traffic-per-FLOP: staged bytes ~ 1/BM + 1/BN,
// so 256^2 halves the load-queue pressure while doubling per-step compute
// cover (96 MFMA/wave/step). 512 threads = 8 waves (2/SIMD, same occupancy
// as R8); each wave owns a 128x64 quadrant: acc 8x4 f32x4 = 128 regs +
// hoisted B-frags 64 + addr ~50 => ~245 <= 256 cap at (512,2) = 1 block/CU.
// LDS: 2 x 64KB dynamic (region layout [kg(4)][row(256)][8 bf16], 16KB each
// of Ah/Al/Bh/Bl per buffer) -> conflict-free ds_read_b128.
// XCD swizzle bijective: nwg = 256/384/256, all %8==0.
// mode 0: O(hi/lo bf16) = resid + selu(acc + bias), resid = Ah+Al at [r][col]
// mode 1: Cf[r*ldc+col] = acc + bias  (fabs on even col), col < Ncols
// mode 3: Cf[r*ldc+col] = acc
__global__ __launch_bounds__(512,2) void k_mfma_gemm(
    const unsigned short* __restrict__ Ah, const unsigned short* __restrict__ Al, int lda,
    const unsigned short* __restrict__ Bh, const unsigned short* __restrict__ Bl, int ldb,
    const float* __restrict__ bias,
    unsigned short* __restrict__ Oh, unsigned short* __restrict__ Ol,
    float* __restrict__ Cf, int ldc,
    int K, int mode, int Ncols)
{
    extern __shared__ unsigned short sm[];   // 2 x 32768 shorts (128 KB)
    const int tid  = threadIdx.x;            // 0..511
    const int w    = tid >> 6;               // 0..7
    const int lane = tid & 63;

    const int gx = gridDim.x;
    const int nwg = gx * gridDim.y;
    const int h = blockIdx.y * gx + blockIdx.x;
    const int t0 = (h & 7) * (nwg >> 3) + (h >> 3);
    const int row0 = (t0 / gx) * BM;
    const int col0 = (t0 - (t0 / gx) * gx) * BN;

    const int wr = w >> 2;                   // 0..1: 128-row band
    const int wc = w & 3;                    // 0..3: 64-col band

    f32x4 acc[8][4] = {};

    // staging geometry: 8 x 16B chunks/thread (2 per region), same count as R8
    // chunk c in region: kg = c>>8 (0..3), row = c&255
    int c0_ = tid, c1_ = tid + 512;

    auto stage = [&](int buf, int k0) {
        #pragma unroll
        for (int i = 0; i < 8; ++i) {
            const int reg = i >> 1;
            const int c   = (i & 1) ? c1_ : c0_;
            const int kg  = c >> 8, r = c & 255;
            const unsigned short* gp;
            if      (reg == 0) gp = Ah + (size_t)(row0 + r)*lda + (k0 + kg*8);
            else if (reg == 1) gp = Al + (size_t)(row0 + r)*lda + (k0 + kg*8);
            else if (reg == 2) gp = Bh + (size_t)(col0 + r)*ldb + (k0 + kg*8);
            else               gp = Bl + (size_t)(col0 + r)*ldb + (k0 + kg*8);
            __builtin_amdgcn_global_load_lds(
                (const __attribute__((address_space(1))) void*)gp,
                (__attribute__((address_space(3))) void*)(&sm[buf*32768 + reg*8192 + (kg*256 + r)*8]),
                16, 0, 0);
        }
    };

    // prologue: stage tile 0 into buffer 0 (8 VMEM ops in flight)
    stage(0, 0);

    const int nt = K >> 5;
    const int kgl = lane >> 4, lr0 = lane & 15;
    for (int t = 0; t < nt; ++t) {
        const int cur = t & 1;
        // issue next tile's loads; buffer cur^1 was last read at iter t-1,
        // separated from these writes by the end-of-iter barrier
        if (t + 1 < nt) stage(cur ^ 1, (t + 1) << 5);

        // wait only for the OLDER 8 loads (tile t); tile t+1's stay in flight
        if (t + 1 < nt) asm volatile("s_waitcnt vmcnt(8)" ::: "memory");
        else            asm volatile("s_waitcnt vmcnt(0)" ::: "memory");
        __builtin_amdgcn_sched_barrier(0);
        __builtin_amdgcn_s_barrier();      // all waves' tile-t loads landed

        const int base = cur*32768;
        s16x8 bh[4], bl[4];
        #pragma unroll
        for (int n = 0; n < 4; ++n) {
            int off = (kgl*256 + wc*64 + n*16 + lr0)*8;
            bh[n] = *(const s16x8*)&sm[base + 16384 + off];
            bl[n] = *(const s16x8*)&sm[base + 24576 + off];
        }
        #pragma unroll
        for (int m = 0; m < 8; ++m) {
            int off = (kgl*256 + wr*128 + m*16 + lr0)*8;
            s16x8 ah = *(const s16x8*)&sm[base + off];
            s16x8 al = *(const s16x8*)&sm[base + 8192 + off];
            #pragma unroll
            for (int n = 0; n < 4; ++n) {
                acc[m][n] = __builtin_amdgcn_mfma_f32_16x16x32_bf16(ah, bh[n], acc[m][n], 0,0,0);
                acc[m][n] = __builtin_amdgcn_mfma_f32_16x16x32_bf16(ah, bl[n], acc[m][n], 0,0,0);
                acc[m][n] = __builtin_amdgcn_mfma_f32_16x16x32_bf16(al, bh[n], acc[m][n], 0,0,0);
            }
        }
        __builtin_amdgcn_s_barrier();      // all waves done reading buf[cur]
    }

    // C/D layout: col = lane&15, row = (lane>>4)*4 + reg
    const int lr = lane & 15, q = lane >> 4;
    if (mode == 0) {
        #pragma unroll
        for (int n = 0; n < 4; ++n) {
            int col = col0 + wc*64 + n*16 + lr;
            float bv = bias[col];
            #pragma unroll
            for (int m = 0; m < 8; ++m) {
                int rb = row0 + wr*128 + m*16 + q*4;
                #pragma unroll
                for (int g = 0; g < 4; ++g) {
                    size_t idx = (size_t)(rb + g)*lda + col;   // lda == N == 512
                    float resid = bf2f(Ah[idx]) + bf2f(Al[idx]);
                    float o = resid + selu_f(acc[m][n][g] + bv);
                    unsigned short hh = f2bf(o);
                    Oh[idx] = hh;
                    Ol[idx] = f2bf(o - bf2f(hh));
                }
            }
        }
    } else if (mode == 1) {
        #pragma unroll
        for (int n = 0; n < 4; ++n) {
            int col = col0 + wc*64 + n*16 + lr;
            if (col < Ncols) {
                float bv = bias[col];
                bool isev = !(col & 1);
                #pragma unroll
                for (int m = 0; m < 8; ++m) {
                    int rb = row0 + wr*128 + m*16 + q*4;
                    #pragma unroll
                    for (int g = 0; g < 4; ++g) {
                        float v = acc[m][n][g] + bv;
                        if (isev) v = fabsf(v);
                        Cf[(size_t)(rb + g)*ldc + col] = v;
                    }
                }
            }
        }
    } else {
        #pragma unroll
        for (int n = 0; n < 4; ++n) {
            int col = col0 + wc*64 + n*16 + lr;
            #pragma unroll
            for (int m = 0; m < 8; ++m) {
                int rb = row0 + wr*128 + m*16 + q*4;
                #pragma unroll
                for (int g = 0; g < 4; ++g)
                    Cf[(size_t)(rb + g)*ldc + col] = acc[m][n][g];
            }
        }
    }
}

// ---------------- small kernels --------------------------------------------

__global__ void k_eproj(const float* __restrict__ ev, const float* __restrict__ w,
                        const float* __restrict__ b, float* __restrict__ e_buf){
    int idx = blockIdx.x*256 + threadIdx.x;        // E_N*H_N = 65536
    int ei = idx >> 9, h = idx & 511;
    float acc = b[h];
    #pragma unroll
    for (int l = 0; l < L_N; ++l) acc = fmaf(ev[ei*L_N+l], w[h*L_N+l], acc);
    e_buf[idx] = acc;
}

__global__ void k_pproj(const float* __restrict__ gp, const float* __restrict__ w,
                        const float* __restrict__ b, float* __restrict__ p_buf){
    int idx = blockIdx.x*256 + threadIdx.x;        // F_N*H_N = 131072
    int f = idx >> 9, h = idx & 511;
    float acc = b[h];
    #pragma unroll 8
    for (int g = 0; g < GP_N; ++g) acc = fmaf(gp[f*GP_N+g], w[h*GP_N+g], acc);
    p_buf[idx] = acc;
}

// x0 = e + p, emitted directly as bf16 hi/lo pair
__global__ void k_xinit_bf(const float4* __restrict__ e_buf, const float4* __restrict__ p_buf,
                           unsigned short* __restrict__ xh, unsigned short* __restrict__ xl){
    int idx = blockIdx.x*256 + threadIdx.x;        // M_ROWS*128 float4 groups
    int h4 = idx & 127;
    int r  = idx >> 7;
    int ei = r >> 8, f = r & 255;
    float4 a = e_buf[ei*128 + h4];
    float4 b = p_buf[f*128 + h4];
    float o[4] = {a.x+b.x, a.y+b.y, a.z+b.z, a.w+b.w};
    unsigned short hh[4], ll[4];
    #pragma unroll
    for (int j = 0; j < 4; ++j) split2(o[j], &hh[j], &ll[j]);
    size_t base = (size_t)r*H_N + h4*4;
    *(ushort4*)&xh[base] = make_ushort4(hh[0], hh[1], hh[2], hh[3]);
    *(ushort4*)&xl[base] = make_ushort4(ll[0], ll[1], ll[2], ll[3]);
}

// generic fp32 -> bf16 hi/lo splitter (4 elems/thread)
__global__ void k_split4(const float4* __restrict__ src, unsigned short* __restrict__ oh,
                         unsigned short* __restrict__ ol, int n4){
    int i = blockIdx.x*256 + threadIdx.x;
    if (i >= n4) return;
    float4 v = src[i];
    float o[4] = {v.x, v.y, v.z, v.w};
    unsigned short hh[4], ll[4];
    #pragma unroll
    for (int j = 0; j < 4; ++j) split2(o[j], &hh[j], &ll[j]);
    *(ushort4*)&oh[(size_t)i*4] = make_ushort4(hh[0], hh[1], hh[2], hh[3]);
    *(ushort4*)&ol[(size_t)i*4] = make_ushort4(ll[0], ll[1], ll[2], ll[3]);
}

// interleaved mag/dith weights: row 2n = w_mag[n], 2n+1 = w_dith[n]; pad rows zero
__global__ void k_wmd(const float* __restrict__ wm, const float* __restrict__ wd,
                      const float* __restrict__ bm, const float* __restrict__ bd,
                      unsigned short* __restrict__ wh, unsigned short* __restrict__ wl,
                      float* __restrict__ bmd){
    int idx = blockIdx.x*256 + threadIdx.x;        // WMD_N*H_N = 393216
    if (idx >= WMD_N*H_N) return;
    int m = idx >> 9, h = idx & 511;
    float v = 0.f;
    if (m < 2*C_N) v = (m & 1) ? wd[(m>>1)*H_N + h] : wm[(m>>1)*H_N + h];
    split2(v, &wh[idx], &wl[idx]);
    if (idx < WMD_N) {
        float b = 0.f;
        if (idx < 2*C_N) b = (idx & 1) ? bd[idx>>1] : bm[idx>>1];
        bmd[idx] = b;
    }
}

// iDFT basis (win * ortho irfft), emitted as bf16 hi/lo, [F2_N][KLD]
__global__ void k_basis_bf(unsigned short* __restrict__ bh, unsigned short* __restrict__ bl){
    int idx = blockIdx.x*256 + threadIdx.x;        // F2_N*KLD = 278528
    if (idx >= F2_N*KLD) return;
    int n = idx / KLD, kr = idx - n*KLD;
    float val = 0.f;
    if (kr < 2*C_N) {
        int k = kr >> 1;
        float wk = (k==0 || k==C_N-1) ? 1.f : 2.f;
        int j = (k*n) & 511;
        float ang = (float)((double)j * 0.01227184630308513);   // 2*pi/512
        float s, c;
        sincosf(ang, &s, &c);
        float wang = (float)((double)n * 0.01227184630308513);
        float win = 0.5f - 0.5f*cosf(wang);
        const float rs = 0.04419417382415922f;                  // 1/sqrt(512)
        val = ((kr & 1) ? -s : c) * wk * win * rs;
    }
    split2(val, &bh[idx], &bl[idx]);
}

// sim argmax: block = event, thread = f (512)
__global__ void k_sim(const float* __restrict__ times, const float* __restrict__ pos,
                      int* __restrict__ pidx){
    __shared__ float sv[512];
    __shared__ int   si[512];
    int e = blockIdx.x, f = threadIdx.x;
    float acc = 0.f;
    #pragma unroll
    for (int d = 0; d < PE_N; ++d) acc = fmaf(times[e*PE_N+d], pos[f*PE_N+d], acc);
    sv[f] = acc; si[f] = f;
    __syncthreads();
    for (int off = 256; off > 0; off >>= 1) {
        if (f < off) {
            float v2 = sv[f+off]; int i2 = si[f+off];
            if (v2 > sv[f] || (v2 == sv[f] && i2 < si[f])) { sv[f]=v2; si[f]=i2; }
        }
        __syncthreads();
    }
    if (f == 0) pidx[e] = si[0];
}

// phase cumsum, k-chunked for coalescing: block = (e, 16 k's), thread = frame f.
__global__ void k_phase(const float* __restrict__ md, const float* __restrict__ noise,
                        unsigned short* __restrict__ ch, unsigned short* __restrict__ cl){
    int k0 = blockIdx.x * KC;          // 17 chunks cover k in [0,272)
    int e  = blockIdx.y;
    int f  = threadIdx.x;              // 256 frames
    size_t row = (size_t)(e*F_N + f);

    float mdv[2*KC];
    const float4* mp = (const float4*)(md + row*MDLD + 2*k0);
    #pragma unroll
    for (int i = 0; i < (2*KC)/4; ++i) *(float4*)&mdv[4*i] = mp[i];

    const int lane = f & 63, wv = f >> 6;
    __shared__ float wsum[KC][4];
    float ph[KC];
    #pragma unroll
    for (int kk = 0; kk < KC; ++kk) {
        int k = k0 + kk;
        float p = 0.f;
        if (k < C_N) {
            float d  = mdv[2*kk+1];
            float nz = noise[(size_t)f*C_N + k];
            float gdk = (float)(3.141592653589793/256.0) * (float)k;
            p = gdk + d*gdk*nz;
        }
        #pragma unroll
        for (int off = 1; off < 64; off <<= 1) {
            float t = __shfl_up(p, off);
            if (lane >= off) p += t;
        }
        if (lane == 63) wsum[kk][wv] = p;
        ph[kk] = p;
    }
    __syncthreads();

    unsigned short oh[2*KC], ol[2*KC];
    #pragma unroll
    for (int kk = 0; kk < KC; ++kk) {
        int k = k0 + kk;
        if (k < C_N) {
            float p = ph[kk];
            #pragma unroll
            for (int i = 0; i < 3; ++i) if (i < wv) p += wsum[kk][i];
            float sv, cv;
            sincosf(p, &sv, &cv);
            float m = mdv[2*kk];
            split2(m*cv, &oh[2*kk],   &ol[2*kk]);
            split2(m*sv, &oh[2*kk+1], &ol[2*kk+1]);
        } else {
            oh[2*kk] = 0; oh[2*kk+1] = 0;
            ol[2*kk] = 0; ol[2*kk+1] = 0;
        }
    }
    size_t o = row*KLD + 2*k0;
    #pragma unroll
    for (int i = 0; i < 4; ++i) {
        ((uint4*)(ch + o))[i] = ((const uint4*)oh)[i];
        ((uint4*)(cl + o))[i] = ((const uint4*)ol)[i];
    }
}

// out[t] = sum_e (OLA frames of event e, shifted by p_e)
__global__ void k_gather(const float* __restrict__ wnd, const int* __restrict__ pidx,
                         float* __restrict__ out){
    __shared__ int sp[E_N];
    int tid = threadIdx.x;
    if (tid < E_N) sp[tid] = pidx[tid]*HOP_N;
    __syncthreads();
    int t = blockIdx.x*256 + tid;
    float acc = 0.f;
    #pragma unroll 4
    for (int e = 0; e < E_N; ++e) {
        int s = t + NSAMP - sp[e];
        if ((unsigned)s < (unsigned)NSAMP) {
            int f1 = s >> 8, n1 = s & 255;
            const float* base = wnd + ((size_t)(e*F_N + f1) << 9);
            acc += base[n1];
            if (f1 > 0) acc += base[n1 + 256 - 512];
        }
    }
    out[t] = acc;
}

// ---------------- launch ---------------------------------------------------
extern "C" void kernel_launch(void* const* d_in, const int* in_sizes, int n_in,
                              void* d_out, int out_size, void* d_ws, size_t ws_size,
                              hipStream_t stream) {
    const float* events  = (const float*)d_in[0];
    const float* times   = (const float*)d_in[1];
    const float* pos     = (const float*)d_in[2];
    const float* gen_pos = (const float*)d_in[3];
    const float* noise   = (const float*)d_in[4];
    const float* w_ee    = (const float*)d_in[5];
    const float* b_ee    = (const float*)d_in[6];
    const float* w_ep    = (const float*)d_in[7];
    const float* b_ep    = (const float*)d_in[8];
    const float* net_w   = (const float*)d_in[9];
    const float* net_b   = (const float*)d_in[10];
    const float* w_mag   = (const float*)d_in[11];
    const float* b_mag   = (const float*)d_in[12];
    const float* w_dith  = (const float*)d_in[13];
    const float* b_dith  = (const float*)d_in[14];
    float* out = (float*)d_out;

    // workspace layout (~182 MB, lifetime-based aliasing)
    char* ws8 = (char*)d_ws;
    unsigned short* xAh = (unsigned short*)(ws8);
    unsigned short* xAl = (unsigned short*)(ws8 + 33554432ull);
    unsigned short* xBh = (unsigned short*)(ws8 + 67108864ull);
    unsigned short* xBl = (unsigned short*)(ws8 + 100663296ull);
    float*          cs32= (float*)(ws8 + 67108864ull);            // 71303168 B
    unsigned short* csh = (unsigned short*)(ws8);                 // 35651584 B
    unsigned short* csl = (unsigned short*)(ws8 + 138412032ull);  // 35651584 B
    float*          bufB= (float*)(ws8 + 67108864ull);            // 64 MB
    char* sp = ws8 + 174063616ull;
    unsigned short* bash = (unsigned short*)sp;  sp += 557056;
    unsigned short* basl = (unsigned short*)sp;  sp += 557056;
    unsigned short* nwh  = (unsigned short*)sp;  sp += 2097152;
    unsigned short* nwl  = (unsigned short*)sp;  sp += 2097152;
    unsigned short* wmdh = (unsigned short*)sp;  sp += 786432;
    unsigned short* wmdl = (unsigned short*)sp;  sp += 786432;
    float* bmd   = (float*)sp;                   sp += 4096;
    float* e_buf = (float*)sp;                   sp += 262144;
    float* p_buf = (float*)sp;                   sp += 524288;
    int*   pidx  = (int*)sp;

    // independent prep
    k_basis_bf<<<(F2_N*KLD + 255)/256, 256, 0, stream>>>(bash, basl);
    k_sim<<<E_N, 512, 0, stream>>>(times, pos, pidx);
    k_split4<<<1024, 256, 0, stream>>>((const float4*)net_w, nwh, nwl, 4*H_N*H_N/4);
    k_wmd<<<(WMD_N*H_N + 255)/256, 256, 0, stream>>>(w_mag, w_dith, b_mag, b_dith, wmdh, wmdl, bmd);
    k_eproj<<<(E_N*H_N)/256, 256, 0, stream>>>(events, w_ee, b_ee, e_buf);
    k_pproj<<<(F_N*H_N)/256, 256, 0, stream>>>(gen_pos, w_ep, b_ep, p_buf);
    k_xinit_bf<<<(M_ROWS*(H_N/4))/256, 256, 0, stream>>>(
        (const float4*)e_buf, (const float4*)p_buf, xAh, xAl);

    const size_t LDS_DYN = 131072;   // 2 x 64KB double buffer

    // 4 residual SELU layers (ping-pong, ends in xA pair)
    unsigned short *ih = xAh, *il = xAl, *oh = xBh, *ol = xBl;
    for (int i = 0; i < 4; ++i) {
        k_mfma_gemm<<<dim3(H_N/BN, M_ROWS/BM), 512, LDS_DYN, stream>>>(
            ih, il, H_N, nwh + (size_t)i*H_N*H_N, nwl + (size_t)i*H_N*H_N, H_N,
            net_b + (size_t)i*H_N, oh, ol, nullptr, 0, H_N, 0, H_N);
        unsigned short* t;
        t = ih; ih = oh; oh = t;
        t = il; il = ol; ol = t;
    }
    // fused mag/dith (interleaved cols) -> cs32 fp32, |.| on even cols
    k_mfma_gemm<<<dim3(WMD_N/BN, M_ROWS/BM), 512, LDS_DYN, stream>>>(
        ih, il, H_N, wmdh, wmdl, H_N, bmd, nullptr, nullptr, cs32, MDLD, H_N, 1, 2*C_N);

    // phase cumsum (k-chunked parallel scan) + sincos -> bf16 hi/lo iDFT operand
    k_phase<<<dim3(17, E_N), 256, 0, stream>>>(cs32, noise, csh, csl);

    // windowed = cs @ basis^T -> bufB fp32 [M][512]
    k_mfma_gemm<<<dim3(F2_N/BN, M_ROWS/BM), 512, LDS_DYN, stream>>>(
        csh, csl, KLD, bash, basl, KLD, nullptr, nullptr, nullptr, bufB, W_N, KLD, 3, F2_N);

    // OLA + impulse-shift gather
    k_gather<<<NSAMP/256, 256, 0, stream>>>(bufB, pidx, out);
}

// Round 15
// 752.761 us; speedup vs baseline: 1.3213x; 1.3213x over previous
//
#include <hip/hip_runtime.h>
#include <math.h>

// Problem constants
#define E_N   128
#define L_N   16
#define PE_N  33
#define F_N   256
#define W_N   512
#define HOP_N 256
#define C_N   257
#define H_N   512
#define GP_N  128
#define F2_N  512
#define NSAMP (F_N*HOP_N)     // 65536
#define M_ROWS (E_N*F_N)      // 32768
#define KLD   544             // bf16 leading dim for iDFT operands (17*32)
#define MDLD  544             // fp32 m/d interleaved buffer leading dim
#define WMD_N 640             // padded interleaved mag/dith weight rows (5*128)
#define KC    16              // k-chunk per phase block

#define BM 128
#define BN 128

typedef float f32x4 __attribute__((ext_vector_type(4)));
typedef short s16x8 __attribute__((ext_vector_type(8)));

__device__ __forceinline__ float selu_f(float x){
    const float alpha = 1.6732632423543772f;
    const float scale = 1.0507009873554805f;
    return scale * (x > 0.f ? x : alpha * expm1f(x));
}
__device__ __forceinline__ unsigned short f2bf(float x){
    unsigned u = __float_as_uint(x);
    return (unsigned short)((u + 0x7fffu + ((u >> 16) & 1u)) >> 16);
}
__device__ __forceinline__ float bf2f(unsigned short h){
    return __uint_as_float((unsigned)h << 16);
}
__device__ __forceinline__ void split2(float x, unsigned short* h, unsigned short* l){
    unsigned short hh = f2bf(x);
    *h = hh;
    *l = f2bf(x - bf2f(hh));
}

// ---------------- MFMA GEMM: C = A(MxK) @ B(NxK)^T via split-bf16 ----------
// VERIFIED BEST (R8/R13, 752us total; GEMM ~123-130us each).
// XCD-aware swizzle (bijective, nwg%8==0 for all launches).
// Double-buffered LDS + COUNTED vmcnt: stage(t+1) issued before the
// pre-compute barrier; s_waitcnt vmcnt(8) drains only tile-t's 8 loads,
// leaving tile-(t+1)'s 8 in flight across the barrier.
// (256,2): 96 arch + 64 acc VGPR, no spill. Final session ledger (GEMM us):
//  sync-single 125 | dbuf-drain0 127 | THIS 123 | >2 waves/SIMD all spill
//  (151-190: R6/R7/R9/R10/R12/R14) | wave-async 290 | 256^2 spill 190.
// Structural floor of the split-bf16 128^2 tile at K=512 on gfx950.
// mode 0: O(hi/lo bf16) = resid + selu(acc + bias), resid = Ah+Al at [r][col]
// mode 1: Cf[r*ldc+col] = acc + bias  (fabs on even col), col < Ncols
// mode 3: Cf[r*ldc+col] = acc
__global__ __launch_bounds__(256,2) void k_mfma_gemm(
    const unsigned short* __restrict__ Ah, const unsigned short* __restrict__ Al, int lda,
    const unsigned short* __restrict__ Bh, const unsigned short* __restrict__ Bl, int ldb,
    const float* __restrict__ bias,
    unsigned short* __restrict__ Oh, unsigned short* __restrict__ Ol,
    float* __restrict__ Cf, int ldc,
    int K, int mode, int Ncols)
{
    // 2 × 32KB buffers; each: 4 tiles of 8KB, K-major tile[kg][row][8 bf16]
    __shared__ unsigned short sm[2][16384];
    const int tid  = threadIdx.x;
    const int w    = tid >> 6;
    const int lane = tid & 63;

    const int gx = gridDim.x;
    const int nwg = gx * gridDim.y;
    const int h = blockIdx.y * gx + blockIdx.x;
    const int t0 = (h & 7) * (nwg >> 3) + (h >> 3);
    const int row0 = (t0 / gx) * BM;
    const int col0 = (t0 - (t0 / gx) * gx) * BN;

    const int wr = w >> 1, wc = w & 1;

    f32x4 acc[4][4] = {};

    // per-thread staging geometry (constant across tiles)
    int ci_[8], kg_[8], r_[8];
    #pragma unroll
    for (int i = 0; i < 8; ++i) {
        int ci = i*256 + w*64 + lane;
        int c  = ci & 511;
        ci_[i] = ci; kg_[i] = c >> 7; r_[i] = c & 127;
    }

    auto stage = [&](int buf, int k0) {
        #pragma unroll
        for (int i = 0; i < 8; ++i) {
            const unsigned short* gp;
            if      (i < 2) gp = Ah + (size_t)(row0 + r_[i])*lda + (k0 + kg_[i]*8);
            else if (i < 4) gp = Al + (size_t)(row0 + r_[i])*lda + (k0 + kg_[i]*8);
            else if (i < 6) gp = Bh + (size_t)(col0 + r_[i])*ldb + (k0 + kg_[i]*8);
            else            gp = Bl + (size_t)(col0 + r_[i])*ldb + (k0 + kg_[i]*8);
            __builtin_amdgcn_global_load_lds(
                (const __attribute__((address_space(1))) void*)gp,
                (__attribute__((address_space(3))) void*)(&sm[buf][ci_[i]*8]),
                16, 0, 0);
        }
    };

    // prologue: stage tile 0 into buffer 0 (8 VMEM ops in flight)
    stage(0, 0);

    const int nt = K >> 5;
    const int kgl = lane >> 4, lr0 = lane & 15;
    for (int t = 0; t < nt; ++t) {
        const int cur = t & 1;
        // issue next tile's loads (8 more VMEM ops; buffer cur^1 was last read
        // at iter t-1, separated from these writes by the end-of-iter barrier)
        if (t + 1 < nt) stage(cur ^ 1, (t + 1) << 5);

        // wait for the OLDER 8 loads (tile t) only; tile t+1's stay in flight
        if (t + 1 < nt) asm volatile("s_waitcnt vmcnt(8)" ::: "memory");
        else            asm volatile("s_waitcnt vmcnt(0)" ::: "memory");
        __builtin_amdgcn_sched_barrier(0);
        __builtin_amdgcn_s_barrier();      // all waves' tile-t loads landed

        s16x8 ah[4], al[4], bh[4], bl[4];
        #pragma unroll
        for (int m = 0; m < 4; ++m) {
            int off = (kgl*128 + wr*64 + m*16 + lr0)*8;
            ah[m] = *(const s16x8*)&sm[cur][off];
            al[m] = *(const s16x8*)&sm[cur][4096 + off];
        }
        #pragma unroll
        for (int n = 0; n < 4; ++n) {
            int off = (kgl*128 + wc*64 + n*16 + lr0)*8;
            bh[n] = *(const s16x8*)&sm[cur][8192 + off];
            bl[n] = *(const s16x8*)&sm[cur][12288 + off];
        }
        #pragma unroll
        for (int m = 0; m < 4; ++m)
            #pragma unroll
            for (int n = 0; n < 4; ++n) {
                acc[m][n] = __builtin_amdgcn_mfma_f32_16x16x32_bf16(ah[m], bh[n], acc[m][n], 0,0,0);
                acc[m][n] = __builtin_amdgcn_mfma_f32_16x16x32_bf16(ah[m], bl[n], acc[m][n], 0,0,0);
                acc[m][n] = __builtin_amdgcn_mfma_f32_16x16x32_bf16(al[m], bh[n], acc[m][n], 0,0,0);
            }
        __builtin_amdgcn_s_barrier();      // all waves done reading buf[cur]
    }

    // C/D layout: col = lane&15, row = (lane>>4)*4 + reg
    const int lr = lane & 15, q = lane >> 4;
    if (mode == 0) {
        #pragma unroll
        for (int n = 0; n < 4; ++n) {
            int col = col0 + wc*64 + n*16 + lr;
            float bv = bias[col];
            #pragma unroll
            for (int m = 0; m < 4; ++m) {
                int rb = row0 + wr*64 + m*16 + q*4;
                #pragma unroll
                for (int g = 0; g < 4; ++g) {
                    size_t idx = (size_t)(rb + g)*lda + col;   // lda == N == 512
                    float resid = bf2f(Ah[idx]) + bf2f(Al[idx]);
                    float o = resid + selu_f(acc[m][n][g] + bv);
                    unsigned short hh = f2bf(o);
                    Oh[idx] = hh;
                    Ol[idx] = f2bf(o - bf2f(hh));
                }
            }
        }
    } else if (mode == 1) {
        #pragma unroll
        for (int n = 0; n < 4; ++n) {
            int col = col0 + wc*64 + n*16 + lr;
            if (col < Ncols) {
                float bv = bias[col];
                bool isev = !(col & 1);
                #pragma unroll
                for (int m = 0; m < 4; ++m) {
                    int rb = row0 + wr*64 + m*16 + q*4;
                    #pragma unroll
                    for (int g = 0; g < 4; ++g) {
                        float v = acc[m][n][g] + bv;
                        if (isev) v = fabsf(v);
                        Cf[(size_t)(rb + g)*ldc + col] = v;
                    }
                }
            }
        }
    } else {
        #pragma unroll
        for (int n = 0; n < 4; ++n) {
            int col = col0 + wc*64 + n*16 + lr;
            #pragma unroll
            for (int m = 0; m < 4; ++m) {
                int rb = row0 + wr*64 + m*16 + q*4;
                #pragma unroll
                for (int g = 0; g < 4; ++g)
                    Cf[(size_t)(rb + g)*ldc + col] = acc[m][n][g];
            }
        }
    }
}

// ---------------- small kernels --------------------------------------------

__global__ void k_eproj(const float* __restrict__ ev, const float* __restrict__ w,
                        const float* __restrict__ b, float* __restrict__ e_buf){
    int idx = blockIdx.x*256 + threadIdx.x;        // E_N*H_N = 65536
    int ei = idx >> 9, h = idx & 511;
    float acc = b[h];
    #pragma unroll
    for (int l = 0; l < L_N; ++l) acc = fmaf(ev[ei*L_N+l], w[h*L_N+l], acc);
    e_buf[idx] = acc;
}

__global__ void k_pproj(const float* __restrict__ gp, const float* __restrict__ w,
                        const float* __restrict__ b, float* __restrict__ p_buf){
    int idx = blockIdx.x*256 + threadIdx.x;        // F_N*H_N = 131072
    int f = idx >> 9, h = idx & 511;
    float acc = b[h];
    #pragma unroll 8
    for (int g = 0; g < GP_N; ++g) acc = fmaf(gp[f*GP_N+g], w[h*GP_N+g], acc);
    p_buf[idx] = acc;
}

// x0 = e + p, emitted directly as bf16 hi/lo pair
__global__ void k_xinit_bf(const float4* __restrict__ e_buf, const float4* __restrict__ p_buf,
                           unsigned short* __restrict__ xh, unsigned short* __restrict__ xl){
    int idx = blockIdx.x*256 + threadIdx.x;        // M_ROWS*128 float4 groups
    int h4 = idx & 127;
    int r  = idx >> 7;
    int ei = r >> 8, f = r & 255;
    float4 a = e_buf[ei*128 + h4];
    float4 b = p_buf[f*128 + h4];
    float o[4] = {a.x+b.x, a.y+b.y, a.z+b.z, a.w+b.w};
    unsigned short hh[4], ll[4];
    #pragma unroll
    for (int j = 0; j < 4; ++j) split2(o[j], &hh[j], &ll[j]);
    size_t base = (size_t)r*H_N + h4*4;
    *(ushort4*)&xh[base] = make_ushort4(hh[0], hh[1], hh[2], hh[3]);
    *(ushort4*)&xl[base] = make_ushort4(ll[0], ll[1], ll[2], ll[3]);
}

// generic fp32 -> bf16 hi/lo splitter (4 elems/thread)
__global__ void k_split4(const float4* __restrict__ src, unsigned short* __restrict__ oh,
                         unsigned short* __restrict__ ol, int n4){
    int i = blockIdx.x*256 + threadIdx.x;
    if (i >= n4) return;
    float4 v = src[i];
    float o[4] = {v.x, v.y, v.z, v.w};
    unsigned short hh[4], ll[4];
    #pragma unroll
    for (int j = 0; j < 4; ++j) split2(o[j], &hh[j], &ll[j]);
    *(ushort4*)&oh[(size_t)i*4] = make_ushort4(hh[0], hh[1], hh[2], hh[3]);
    *(ushort4*)&ol[(size_t)i*4] = make_ushort4(ll[0], ll[1], ll[2], ll[3]);
}

// interleaved mag/dith weights: row 2n = w_mag[n], 2n+1 = w_dith[n]; pad rows zero
__global__ void k_wmd(const float* __restrict__ wm, const float* __restrict__ wd,
                      const float* __restrict__ bm, const float* __restrict__ bd,
                      unsigned short* __restrict__ wh, unsigned short* __restrict__ wl,
                      float* __restrict__ bmd){
    int idx = blockIdx.x*256 + threadIdx.x;        // WMD_N*H_N = 327680
    if (idx >= WMD_N*H_N) return;
    int m = idx >> 9, h = idx & 511;
    float v = 0.f;
    if (m < 2*C_N) v = (m & 1) ? wd[(m>>1)*H_N + h] : wm[(m>>1)*H_N + h];
    split2(v, &wh[idx], &wl[idx]);
    if (idx < WMD_N) {
        float b = 0.f;
        if (idx < 2*C_N) b = (idx & 1) ? bd[idx>>1] : bm[idx>>1];
        bmd[idx] = b;
    }
}

// iDFT basis (win * ortho irfft), emitted as bf16 hi/lo, [F2_N][KLD]
__global__ void k_basis_bf(unsigned short* __restrict__ bh, unsigned short* __restrict__ bl){
    int idx = blockIdx.x*256 + threadIdx.x;        // F2_N*KLD = 278528
    if (idx >= F2_N*KLD) return;
    int n = idx / KLD, kr = idx - n*KLD;
    float val = 0.f;
    if (kr < 2*C_N) {
        int k = kr >> 1;
        float wk = (k==0 || k==C_N-1) ? 1.f : 2.f;
        int j = (k*n) & 511;
        float ang = (float)((double)j * 0.01227184630308513);   // 2*pi/512
        float s, c;
        sincosf(ang, &s, &c);
        float wang = (float)((double)n * 0.01227184630308513);
        float win = 0.5f - 0.5f*cosf(wang);
        const float rs = 0.04419417382415922f;                  // 1/sqrt(512)
        val = ((kr & 1) ? -s : c) * wk * win * rs;
    }
    split2(val, &bh[idx], &bl[idx]);
}

// sim argmax: block = event, thread = f (512)
__global__ void k_sim(const float* __restrict__ times, const float* __restrict__ pos,
                      int* __restrict__ pidx){
    __shared__ float sv[512];
    __shared__ int   si[512];
    int e = blockIdx.x, f = threadIdx.x;
    float acc = 0.f;
    #pragma unroll
    for (int d = 0; d < PE_N; ++d) acc = fmaf(times[e*PE_N+d], pos[f*PE_N+d], acc);
    sv[f] = acc; si[f] = f;
    __syncthreads();
    for (int off = 256; off > 0; off >>= 1) {
        if (f < off) {
            float v2 = sv[f+off]; int i2 = si[f+off];
            if (v2 > sv[f] || (v2 == sv[f] && i2 < si[f])) { sv[f]=v2; si[f]=i2; }
        }
        __syncthreads();
    }
    if (f == 0) pidx[e] = si[0];
}

// phase cumsum, k-chunked for coalescing: block = (e, 16 k's), thread = frame f.
__global__ void k_phase(const float* __restrict__ md, const float* __restrict__ noise,
                        unsigned short* __restrict__ ch, unsigned short* __restrict__ cl){
    int k0 = blockIdx.x * KC;          // 17 chunks cover k in [0,272)
    int e  = blockIdx.y;
    int f  = threadIdx.x;              // 256 frames
    size_t row = (size_t)(e*F_N + f);

    float mdv[2*KC];
    const float4* mp = (const float4*)(md + row*MDLD + 2*k0);
    #pragma unroll
    for (int i = 0; i < (2*KC)/4; ++i) *(float4*)&mdv[4*i] = mp[i];

    const int lane = f & 63, wv = f >> 6;
    __shared__ float wsum[KC][4];
    float ph[KC];
    #pragma unroll
    for (int kk = 0; kk < KC; ++kk) {
        int k = k0 + kk;
        float p = 0.f;
        if (k < C_N) {
            float d  = mdv[2*kk+1];
            float nz = noise[(size_t)f*C_N + k];
            float gdk = (float)(3.141592653589793/256.0) * (float)k;
            p = gdk + d*gdk*nz;
        }
        #pragma unroll
        for (int off = 1; off < 64; off <<= 1) {
            float t = __shfl_up(p, off);
            if (lane >= off) p += t;
        }
        if (lane == 63) wsum[kk][wv] = p;
        ph[kk] = p;
    }
    __syncthreads();

    unsigned short oh[2*KC], ol[2*KC];
    #pragma unroll
    for (int kk = 0; kk < KC; ++kk) {
        int k = k0 + kk;
        if (k < C_N) {
            float p = ph[kk];
            #pragma unroll
            for (int i = 0; i < 3; ++i) if (i < wv) p += wsum[kk][i];
            float sv, cv;
            sincosf(p, &sv, &cv);
            float m = mdv[2*kk];
            split2(m*cv, &oh[2*kk],   &ol[2*kk]);
            split2(m*sv, &oh[2*kk+1], &ol[2*kk+1]);
        } else {
            oh[2*kk] = 0; oh[2*kk+1] = 0;
            ol[2*kk] = 0; ol[2*kk+1] = 0;
        }
    }
    size_t o = row*KLD + 2*k0;
    #pragma unroll
    for (int i = 0; i < 4; ++i) {
        ((uint4*)(ch + o))[i] = ((const uint4*)oh)[i];
        ((uint4*)(cl + o))[i] = ((const uint4*)ol)[i];
    }
}

// out[t] = sum_e (OLA frames of event e, shifted by p_e)
__global__ void k_gather(const float* __restrict__ wnd, const int* __restrict__ pidx,
                         float* __restrict__ out){
    __shared__ int sp[E_N];
    int tid = threadIdx.x;
    if (tid < E_N) sp[tid] = pidx[tid]*HOP_N;
    __syncthreads();
    int t = blockIdx.x*256 + tid;
    float acc = 0.f;
    #pragma unroll 4
    for (int e = 0; e < E_N; ++e) {
        int s = t + NSAMP - sp[e];
        if ((unsigned)s < (unsigned)NSAMP) {
            int f1 = s >> 8, n1 = s & 255;
            const float* base = wnd + ((size_t)(e*F_N + f1) << 9);
            acc += base[n1];
            if (f1 > 0) acc += base[n1 + 256 - 512];
        }
    }
    out[t] = acc;
}

// ---------------- launch ---------------------------------------------------
extern "C" void kernel_launch(void* const* d_in, const int* in_sizes, int n_in,
                              void* d_out, int out_size, void* d_ws, size_t ws_size,
                              hipStream_t stream) {
    const float* events  = (const float*)d_in[0];
    const float* times   = (const float*)d_in[1];
    const float* pos     = (const float*)d_in[2];
    const float* gen_pos = (const float*)d_in[3];
    const float* noise   = (const float*)d_in[4];
    const float* w_ee    = (const float*)d_in[5];
    const float* b_ee    = (const float*)d_in[6];
    const float* w_ep    = (const float*)d_in[7];
    const float* b_ep    = (const float*)d_in[8];
    const float* net_w   = (const float*)d_in[9];
    const float* net_b   = (const float*)d_in[10];
    const float* w_mag   = (const float*)d_in[11];
    const float* b_mag   = (const float*)d_in[12];
    const float* w_dith  = (const float*)d_in[13];
    const float* b_dith  = (const float*)d_in[14];
    float* out = (float*)d_out;

    // workspace layout (~181.5 MB, lifetime-based aliasing)
    char* ws8 = (char*)d_ws;
    unsigned short* xAh = (unsigned short*)(ws8);
    unsigned short* xAl = (unsigned short*)(ws8 + 33554432ull);
    unsigned short* xBh = (unsigned short*)(ws8 + 67108864ull);
    unsigned short* xBl = (unsigned short*)(ws8 + 100663296ull);
    float*          cs32= (float*)(ws8 + 67108864ull);            // 71303168 B
    unsigned short* csh = (unsigned short*)(ws8);                 // 35651584 B
    unsigned short* csl = (unsigned short*)(ws8 + 138412032ull);  // 35651584 B
    float*          bufB= (float*)(ws8 + 67108864ull);            // 64 MB
    char* sp = ws8 + 174063616ull;
    unsigned short* bash = (unsigned short*)sp;  sp += 557056;
    unsigned short* basl = (unsigned short*)sp;  sp += 557056;
    unsigned short* nwh  = (unsigned short*)sp;  sp += 2097152;
    unsigned short* nwl  = (unsigned short*)sp;  sp += 2097152;
    unsigned short* wmdh = (unsigned short*)sp;  sp += 655360;
    unsigned short* wmdl = (unsigned short*)sp;  sp += 655360;
    float* bmd   = (float*)sp;                   sp += 4096;
    float* e_buf = (float*)sp;                   sp += 262144;
    float* p_buf = (float*)sp;                   sp += 524288;
    int*   pidx  = (int*)sp;

    // independent prep
    k_basis_bf<<<(F2_N*KLD + 255)/256, 256, 0, stream>>>(bash, basl);
    k_sim<<<E_N, 512, 0, stream>>>(times, pos, pidx);
    k_split4<<<1024, 256, 0, stream>>>((const float4*)net_w, nwh, nwl, 4*H_N*H_N/4);
    k_wmd<<<(WMD_N*H_N + 255)/256, 256, 0, stream>>>(w_mag, w_dith, b_mag, b_dith, wmdh, wmdl, bmd);
    k_eproj<<<(E_N*H_N)/256, 256, 0, stream>>>(events, w_ee, b_ee, e_buf);
    k_pproj<<<(F_N*H_N)/256, 256, 0, stream>>>(gen_pos, w_ep, b_ep, p_buf);
    k_xinit_bf<<<(M_ROWS*(H_N/4))/256, 256, 0, stream>>>(
        (const float4*)e_buf, (const float4*)p_buf, xAh, xAl);

    // 4 residual SELU layers (ping-pong, ends in xA pair)
    unsigned short *ih = xAh, *il = xAl, *oh = xBh, *ol = xBl;
    for (int i = 0; i < 4; ++i) {
        k_mfma_gemm<<<dim3(H_N/BN, M_ROWS/BM), 256, 0, stream>>>(
            ih, il, H_N, nwh + (size_t)i*H_N*H_N, nwl + (size_t)i*H_N*H_N, H_N,
            net_b + (size_t)i*H_N, oh, ol, nullptr, 0, H_N, 0, H_N);
        unsigned short* t;
        t = ih; ih = oh; oh = t;
        t = il; il = ol; ol = t;
    }
    // fused mag/dith (interleaved cols) -> cs32 fp32, |.| on even cols
    k_mfma_gemm<<<dim3(WMD_N/BN, M_ROWS/BM), 256, 0, stream>>>(
        ih, il, H_N, wmdh, wmdl, H_N, bmd, nullptr, nullptr, cs32, MDLD, H_N, 1, 2*C_N);

    // phase cumsum (k-chunked parallel scan) + sincos -> bf16 hi/lo iDFT operand
    k_phase<<<dim3(17, E_N), 256, 0, stream>>>(cs32, noise, csh, csl);

    // windowed = cs @ basis^T -> bufB fp32 [M][512]
    k_mfma_gemm<<<dim3(F2_N/BN, M_ROWS/BM), 256, 0, stream>>>(
        csh, csl, KLD, bash, basl, KLD, nullptr, nullptr, nullptr, bufB, W_N, KLD, 3, F2_N);

    // OLA + impulse-shift gather
    k_gather<<<NSAMP/256, 256, 0, stream>>>(bufB, pidx, out);
}

// Round 16
// 737.589 us; speedup vs baseline: 1.3485x; 1.0206x over previous
//
#include <hip/hip_runtime.h>
#include <math.h>

// Problem constants
#define E_N   128
#define L_N   16
#define PE_N  33
#define F_N   256
#define W_N   512
#define HOP_N 256
#define C_N   257
#define H_N   512
#define GP_N  128
#define F2_N  512
#define NSAMP (F_N*HOP_N)     // 65536
#define M_ROWS (E_N*F_N)      // 32768
#define KLD   544             // bf16 leading dim for iDFT operands (17*32)
#define MDLD  544             // fp32 m/d interleaved buffer leading dim
#define WMD_N 640             // padded interleaved mag/dith weight rows (5*128)
#define KC    16              // k-chunk per phase block

#define BM 128
#define BN 128

typedef float f32x4 __attribute__((ext_vector_type(4)));
typedef short s16x8 __attribute__((ext_vector_type(8)));

__device__ __forceinline__ float selu_f(float x){
    const float alpha = 1.6732632423543772f;
    const float scale = 1.0507009873554805f;
    return scale * (x > 0.f ? x : alpha * expm1f(x));
}
__device__ __forceinline__ unsigned short f2bf(float x){
    unsigned u = __float_as_uint(x);
    return (unsigned short)((u + 0x7fffu + ((u >> 16) & 1u)) >> 16);
}
__device__ __forceinline__ float bf2f(unsigned short h){
    return __uint_as_float((unsigned)h << 16);
}
__device__ __forceinline__ void split2(float x, unsigned short* h, unsigned short* l){
    unsigned short hh = f2bf(x);
    *h = hh;
    *l = f2bf(x - bf2f(hh));
}

// ---------------- MFMA GEMM: C = A(MxK) @ B(NxK)^T via split-bf16 ----------
// VERIFIED BEST (R8/R13/R15, 752us total; GEMM ~123-130us each).
// XCD-aware swizzle (bijective, nwg%8==0 for all launches).
// Double-buffered LDS + COUNTED vmcnt: stage(t+1) issued before the
// pre-compute barrier; s_waitcnt vmcnt(8) drains only tile-t's 8 loads,
// leaving tile-(t+1)'s 8 in flight across the barrier.
// (256,2): 96 arch + 64 acc VGPR, no spill.
// mode 0: O(hi/lo bf16) = resid + selu(acc + bias), resid = Ah+Al at [r][col]
// mode 1: Cf[r*ldc+col] = acc + bias  (fabs on even col), col < Ncols
// mode 3: Cf[r*ldc+col] = acc
__global__ __launch_bounds__(256,2) void k_mfma_gemm(
    const unsigned short* __restrict__ Ah, const unsigned short* __restrict__ Al, int lda,
    const unsigned short* __restrict__ Bh, const unsigned short* __restrict__ Bl, int ldb,
    const float* __restrict__ bias,
    unsigned short* __restrict__ Oh, unsigned short* __restrict__ Ol,
    float* __restrict__ Cf, int ldc,
    int K, int mode, int Ncols)
{
    // 2 × 32KB buffers; each: 4 tiles of 8KB, K-major tile[kg][row][8 bf16]
    __shared__ unsigned short sm[2][16384];
    const int tid  = threadIdx.x;
    const int w    = tid >> 6;
    const int lane = tid & 63;

    const int gx = gridDim.x;
    const int nwg = gx * gridDim.y;
    const int h = blockIdx.y * gx + blockIdx.x;
    const int t0 = (h & 7) * (nwg >> 3) + (h >> 3);
    const int row0 = (t0 / gx) * BM;
    const int col0 = (t0 - (t0 / gx) * gx) * BN;

    const int wr = w >> 1, wc = w & 1;

    f32x4 acc[4][4] = {};

    // per-thread staging geometry (constant across tiles)
    int ci_[8], kg_[8], r_[8];
    #pragma unroll
    for (int i = 0; i < 8; ++i) {
        int ci = i*256 + w*64 + lane;
        int c  = ci & 511;
        ci_[i] = ci; kg_[i] = c >> 7; r_[i] = c & 127;
    }

    auto stage = [&](int buf, int k0) {
        #pragma unroll
        for (int i = 0; i < 8; ++i) {
            const unsigned short* gp;
            if      (i < 2) gp = Ah + (size_t)(row0 + r_[i])*lda + (k0 + kg_[i]*8);
            else if (i < 4) gp = Al + (size_t)(row0 + r_[i])*lda + (k0 + kg_[i]*8);
            else if (i < 6) gp = Bh + (size_t)(col0 + r_[i])*ldb + (k0 + kg_[i]*8);
            else            gp = Bl + (size_t)(col0 + r_[i])*ldb + (k0 + kg_[i]*8);
            __builtin_amdgcn_global_load_lds(
                (const __attribute__((address_space(1))) void*)gp,
                (__attribute__((address_space(3))) void*)(&sm[buf][ci_[i]*8]),
                16, 0, 0);
        }
    };

    // prologue: stage tile 0 into buffer 0 (8 VMEM ops in flight)
    stage(0, 0);

    const int nt = K >> 5;
    const int kgl = lane >> 4, lr0 = lane & 15;
    for (int t = 0; t < nt; ++t) {
        const int cur = t & 1;
        if (t + 1 < nt) stage(cur ^ 1, (t + 1) << 5);

        if (t + 1 < nt) asm volatile("s_waitcnt vmcnt(8)" ::: "memory");
        else            asm volatile("s_waitcnt vmcnt(0)" ::: "memory");
        __builtin_amdgcn_sched_barrier(0);
        __builtin_amdgcn_s_barrier();      // all waves' tile-t loads landed

        s16x8 ah[4], al[4], bh[4], bl[4];
        #pragma unroll
        for (int m = 0; m < 4; ++m) {
            int off = (kgl*128 + wr*64 + m*16 + lr0)*8;
            ah[m] = *(const s16x8*)&sm[cur][off];
            al[m] = *(const s16x8*)&sm[cur][4096 + off];
        }
        #pragma unroll
        for (int n = 0; n < 4; ++n) {
            int off = (kgl*128 + wc*64 + n*16 + lr0)*8;
            bh[n] = *(const s16x8*)&sm[cur][8192 + off];
            bl[n] = *(const s16x8*)&sm[cur][12288 + off];
        }
        #pragma unroll
        for (int m = 0; m < 4; ++m)
            #pragma unroll
            for (int n = 0; n < 4; ++n) {
                acc[m][n] = __builtin_amdgcn_mfma_f32_16x16x32_bf16(ah[m], bh[n], acc[m][n], 0,0,0);
                acc[m][n] = __builtin_amdgcn_mfma_f32_16x16x32_bf16(ah[m], bl[n], acc[m][n], 0,0,0);
                acc[m][n] = __builtin_amdgcn_mfma_f32_16x16x32_bf16(al[m], bh[n], acc[m][n], 0,0,0);
            }
        __builtin_amdgcn_s_barrier();      // all waves done reading buf[cur]
    }

    // C/D layout: col = lane&15, row = (lane>>4)*4 + reg
    const int lr = lane & 15, q = lane >> 4;
    if (mode == 0) {
        #pragma unroll
        for (int n = 0; n < 4; ++n) {
            int col = col0 + wc*64 + n*16 + lr;
            float bv = bias[col];
            #pragma unroll
            for (int m = 0; m < 4; ++m) {
                int rb = row0 + wr*64 + m*16 + q*4;
                #pragma unroll
                for (int g = 0; g < 4; ++g) {
                    size_t idx = (size_t)(rb + g)*lda + col;   // lda == N == 512
                    float resid = bf2f(Ah[idx]) + bf2f(Al[idx]);
                    float o = resid + selu_f(acc[m][n][g] + bv);
                    unsigned short hh = f2bf(o);
                    Oh[idx] = hh;
                    Ol[idx] = f2bf(o - bf2f(hh));
                }
            }
        }
    } else if (mode == 1) {
        #pragma unroll
        for (int n = 0; n < 4; ++n) {
            int col = col0 + wc*64 + n*16 + lr;
            if (col < Ncols) {
                float bv = bias[col];
                bool isev = !(col & 1);
                #pragma unroll
                for (int m = 0; m < 4; ++m) {
                    int rb = row0 + wr*64 + m*16 + q*4;
                    #pragma unroll
                    for (int g = 0; g < 4; ++g) {
                        float v = acc[m][n][g] + bv;
                        if (isev) v = fabsf(v);
                        Cf[(size_t)(rb + g)*ldc + col] = v;
                    }
                }
            }
        }
    } else {
        #pragma unroll
        for (int n = 0; n < 4; ++n) {
            int col = col0 + wc*64 + n*16 + lr;
            #pragma unroll
            for (int m = 0; m < 4; ++m) {
                int rb = row0 + wr*64 + m*16 + q*4;
                #pragma unroll
                for (int g = 0; g < 4; ++g)
                    Cf[(size_t)(rb + g)*ldc + col] = acc[m][n][g];
            }
        }
    }
}

// ---------------- MFMA GEMM, single-bf16 B (iDFT only): C = (Ah+Al) @ Bw^T --
// B rounded to ONE bf16 (basis enters output linearly; 2^-9 relative on a
// |val|<=0.088 operand, incoherent over 514 terms -> <<0.125 absmax budget).
// 3 staged regions (Ah, Al, Bw): 6 loads/thread (vmcnt(6)), 32 MFMA/step,
// frag live set 12 s16x8 = 48 regs (vs 64), LDS 2x24KB = 48KB.
// (256,3): first no-spill shot at 3 blocks/CU — working set ~80 arch fits
// the ~106 available (170 cap - 64 acc). Falsifier: WRITE > 85MB = spill.
__global__ __launch_bounds__(256,3) void k_mfma_gemm_b1(
    const unsigned short* __restrict__ Ah, const unsigned short* __restrict__ Al, int lda,
    const unsigned short* __restrict__ Bw, int ldb,
    float* __restrict__ Cf, int ldc,
    int K)
{
    // 2 × 24KB buffers; regions Ah[0..4095], Al[4096..8191], Bw[8192..12287]
    // each region K-major [kg(4)][row(128)][8 bf16]
    __shared__ unsigned short sm[2][12288];
    const int tid  = threadIdx.x;
    const int w    = tid >> 6;
    const int lane = tid & 63;

    const int gx = gridDim.x;
    const int nwg = gx * gridDim.y;
    const int h = blockIdx.y * gx + blockIdx.x;
    const int t0 = (h & 7) * (nwg >> 3) + (h >> 3);
    const int row0 = (t0 / gx) * BM;
    const int col0 = (t0 - (t0 / gx) * gx) * BN;

    const int wr = w >> 1, wc = w & 1;

    f32x4 acc[4][4] = {};

    // staging: 6 chunks/thread; chunk i: region = i>>1, ci = (i&1)*256+tid
    int ci_[6], kg_[6], r_[6];
    #pragma unroll
    for (int i = 0; i < 6; ++i) {
        int ci = (i & 1)*256 + tid;       // 0..511 within region
        ci_[i] = ci; kg_[i] = ci >> 7; r_[i] = ci & 127;
    }

    auto stage = [&](int buf, int k0) {
        #pragma unroll
        for (int i = 0; i < 6; ++i) {
            const int reg = i >> 1;
            const unsigned short* gp;
            if      (reg == 0) gp = Ah + (size_t)(row0 + r_[i])*lda + (k0 + kg_[i]*8);
            else if (reg == 1) gp = Al + (size_t)(row0 + r_[i])*lda + (k0 + kg_[i]*8);
            else               gp = Bw + (size_t)(col0 + r_[i])*ldb + (k0 + kg_[i]*8);
            __builtin_amdgcn_global_load_lds(
                (const __attribute__((address_space(1))) void*)gp,
                (__attribute__((address_space(3))) void*)(&sm[buf][reg*4096 + ci_[i]*8]),
                16, 0, 0);
        }
    };

    stage(0, 0);

    const int nt = K >> 5;
    const int kgl = lane >> 4, lr0 = lane & 15;
    for (int t = 0; t < nt; ++t) {
        const int cur = t & 1;
        if (t + 1 < nt) stage(cur ^ 1, (t + 1) << 5);

        if (t + 1 < nt) asm volatile("s_waitcnt vmcnt(6)" ::: "memory");
        else            asm volatile("s_waitcnt vmcnt(0)" ::: "memory");
        __builtin_amdgcn_sched_barrier(0);
        __builtin_amdgcn_s_barrier();

        s16x8 ah[4], al[4], bw[4];
        #pragma unroll
        for (int m = 0; m < 4; ++m) {
            int off = (kgl*128 + wr*64 + m*16 + lr0)*8;
            ah[m] = *(const s16x8*)&sm[cur][off];
            al[m] = *(const s16x8*)&sm[cur][4096 + off];
        }
        #pragma unroll
        for (int n = 0; n < 4; ++n) {
            int off = (kgl*128 + wc*64 + n*16 + lr0)*8;
            bw[n] = *(const s16x8*)&sm[cur][8192 + off];
        }
        #pragma unroll
        for (int m = 0; m < 4; ++m)
            #pragma unroll
            for (int n = 0; n < 4; ++n) {
                acc[m][n] = __builtin_amdgcn_mfma_f32_16x16x32_bf16(ah[m], bw[n], acc[m][n], 0,0,0);
                acc[m][n] = __builtin_amdgcn_mfma_f32_16x16x32_bf16(al[m], bw[n], acc[m][n], 0,0,0);
            }
        __builtin_amdgcn_s_barrier();
    }

    const int lr = lane & 15, q = lane >> 4;
    #pragma unroll
    for (int n = 0; n < 4; ++n) {
        int col = col0 + wc*64 + n*16 + lr;
        #pragma unroll
        for (int m = 0; m < 4; ++m) {
            int rb = row0 + wr*64 + m*16 + q*4;
            #pragma unroll
            for (int g = 0; g < 4; ++g)
                Cf[(size_t)(rb + g)*ldc + col] = acc[m][n][g];
        }
    }
}

// ---------------- small kernels --------------------------------------------

__global__ void k_eproj(const float* __restrict__ ev, const float* __restrict__ w,
                        const float* __restrict__ b, float* __restrict__ e_buf){
    int idx = blockIdx.x*256 + threadIdx.x;        // E_N*H_N = 65536
    int ei = idx >> 9, h = idx & 511;
    float acc = b[h];
    #pragma unroll
    for (int l = 0; l < L_N; ++l) acc = fmaf(ev[ei*L_N+l], w[h*L_N+l], acc);
    e_buf[idx] = acc;
}

__global__ void k_pproj(const float* __restrict__ gp, const float* __restrict__ w,
                        const float* __restrict__ b, float* __restrict__ p_buf){
    int idx = blockIdx.x*256 + threadIdx.x;        // F_N*H_N = 131072
    int f = idx >> 9, h = idx & 511;
    float acc = b[h];
    #pragma unroll 8
    for (int g = 0; g < GP_N; ++g) acc = fmaf(gp[f*GP_N+g], w[h*GP_N+g], acc);
    p_buf[idx] = acc;
}

// x0 = e + p, emitted directly as bf16 hi/lo pair
__global__ void k_xinit_bf(const float4* __restrict__ e_buf, const float4* __restrict__ p_buf,
                           unsigned short* __restrict__ xh, unsigned short* __restrict__ xl){
    int idx = blockIdx.x*256 + threadIdx.x;        // M_ROWS*128 float4 groups
    int h4 = idx & 127;
    int r  = idx >> 7;
    int ei = r >> 8, f = r & 255;
    float4 a = e_buf[ei*128 + h4];
    float4 b = p_buf[f*128 + h4];
    float o[4] = {a.x+b.x, a.y+b.y, a.z+b.z, a.w+b.w};
    unsigned short hh[4], ll[4];
    #pragma unroll
    for (int j = 0; j < 4; ++j) split2(o[j], &hh[j], &ll[j]);
    size_t base = (size_t)r*H_N + h4*4;
    *(ushort4*)&xh[base] = make_ushort4(hh[0], hh[1], hh[2], hh[3]);
    *(ushort4*)&xl[base] = make_ushort4(ll[0], ll[1], ll[2], ll[3]);
}

// generic fp32 -> bf16 hi/lo splitter (4 elems/thread)
__global__ void k_split4(const float4* __restrict__ src, unsigned short* __restrict__ oh,
                         unsigned short* __restrict__ ol, int n4){
    int i = blockIdx.x*256 + threadIdx.x;
    if (i >= n4) return;
    float4 v = src[i];
    float o[4] = {v.x, v.y, v.z, v.w};
    unsigned short hh[4], ll[4];
    #pragma unroll
    for (int j = 0; j < 4; ++j) split2(o[j], &hh[j], &ll[j]);
    *(ushort4*)&oh[(size_t)i*4] = make_ushort4(hh[0], hh[1], hh[2], hh[3]);
    *(ushort4*)&ol[(size_t)i*4] = make_ushort4(ll[0], ll[1], ll[2], ll[3]);
}

// interleaved mag/dith weights: row 2n = w_mag[n], 2n+1 = w_dith[n]; pad rows zero
__global__ void k_wmd(const float* __restrict__ wm, const float* __restrict__ wd,
                      const float* __restrict__ bm, const float* __restrict__ bd,
                      unsigned short* __restrict__ wh, unsigned short* __restrict__ wl,
                      float* __restrict__ bmd){
    int idx = blockIdx.x*256 + threadIdx.x;        // WMD_N*H_N = 327680
    if (idx >= WMD_N*H_N) return;
    int m = idx >> 9, h = idx & 511;
    float v = 0.f;
    if (m < 2*C_N) v = (m & 1) ? wd[(m>>1)*H_N + h] : wm[(m>>1)*H_N + h];
    split2(v, &wh[idx], &wl[idx]);
    if (idx < WMD_N) {
        float b = 0.f;
        if (idx < 2*C_N) b = (idx & 1) ? bd[idx>>1] : bm[idx>>1];
        bmd[idx] = b;
    }
}

// iDFT basis (win * ortho irfft), emitted as SINGLE bf16, [F2_N][KLD]
__global__ void k_basis_b1(unsigned short* __restrict__ bh){
    int idx = blockIdx.x*256 + threadIdx.x;        // F2_N*KLD = 278528
    if (idx >= F2_N*KLD) return;
    int n = idx / KLD, kr = idx - n*KLD;
    float val = 0.f;
    if (kr < 2*C_N) {
        int k = kr >> 1;
        float wk = (k==0 || k==C_N-1) ? 1.f : 2.f;
        int j = (k*n) & 511;
        float ang = (float)((double)j * 0.01227184630308513);   // 2*pi/512
        float s, c;
        sincosf(ang, &s, &c);
        float wang = (float)((double)n * 0.01227184630308513);
        float win = 0.5f - 0.5f*cosf(wang);
        const float rs = 0.04419417382415922f;                  // 1/sqrt(512)
        val = ((kr & 1) ? -s : c) * wk * win * rs;
    }
    bh[idx] = f2bf(val);
}

// sim argmax: block = event, thread = f (512)
__global__ void k_sim(const float* __restrict__ times, const float* __restrict__ pos,
                      int* __restrict__ pidx){
    __shared__ float sv[512];
    __shared__ int   si[512];
    int e = blockIdx.x, f = threadIdx.x;
    float acc = 0.f;
    #pragma unroll
    for (int d = 0; d < PE_N; ++d) acc = fmaf(times[e*PE_N+d], pos[f*PE_N+d], acc);
    sv[f] = acc; si[f] = f;
    __syncthreads();
    for (int off = 256; off > 0; off >>= 1) {
        if (f < off) {
            float v2 = sv[f+off]; int i2 = si[f+off];
            if (v2 > sv[f] || (v2 == sv[f] && i2 < si[f])) { sv[f]=v2; si[f]=i2; }
        }
        __syncthreads();
    }
    if (f == 0) pidx[e] = si[0];
}

// phase cumsum, k-chunked for coalescing: block = (e, 16 k's), thread = frame f.
__global__ void k_phase(const float* __restrict__ md, const float* __restrict__ noise,
                        unsigned short* __restrict__ ch, unsigned short* __restrict__ cl){
    int k0 = blockIdx.x * KC;          // 17 chunks cover k in [0,272)
    int e  = blockIdx.y;
    int f  = threadIdx.x;              // 256 frames
    size_t row = (size_t)(e*F_N + f);

    float mdv[2*KC];
    const float4* mp = (const float4*)(md + row*MDLD + 2*k0);
    #pragma unroll
    for (int i = 0; i < (2*KC)/4; ++i) *(float4*)&mdv[4*i] = mp[i];

    const int lane = f & 63, wv = f >> 6;
    __shared__ float wsum[KC][4];
    float ph[KC];
    #pragma unroll
    for (int kk = 0; kk < KC; ++kk) {
        int k = k0 + kk;
        float p = 0.f;
        if (k < C_N) {
            float d  = mdv[2*kk+1];
            float nz = noise[(size_t)f*C_N + k];
            float gdk = (float)(3.141592653589793/256.0) * (float)k;
            p = gdk + d*gdk*nz;
        }
        #pragma unroll
        for (int off = 1; off < 64; off <<= 1) {
            float t = __shfl_up(p, off);
            if (lane >= off) p += t;
        }
        if (lane == 63) wsum[kk][wv] = p;
        ph[kk] = p;
    }
    __syncthreads();

    unsigned short oh[2*KC], ol[2*KC];
    #pragma unroll
    for (int kk = 0; kk < KC; ++kk) {
        int k = k0 + kk;
        if (k < C_N) {
            float p = ph[kk];
            #pragma unroll
            for (int i = 0; i < 3; ++i) if (i < wv) p += wsum[kk][i];
            float sv, cv;
            sincosf(p, &sv, &cv);
            float m = mdv[2*kk];
            split2(m*cv, &oh[2*kk],   &ol[2*kk]);
            split2(m*sv, &oh[2*kk+1], &ol[2*kk+1]);
        } else {
            oh[2*kk] = 0; oh[2*kk+1] = 0;
            ol[2*kk] = 0; ol[2*kk+1] = 0;
        }
    }
    size_t o = row*KLD + 2*k0;
    #pragma unroll
    for (int i = 0; i < 4; ++i) {
        ((uint4*)(ch + o))[i] = ((const uint4*)oh)[i];
        ((uint4*)(cl + o))[i] = ((const uint4*)ol)[i];
    }
}

// out[t] = sum_e (OLA frames of event e, shifted by p_e)
__global__ void k_gather(const float* __restrict__ wnd, const int* __restrict__ pidx,
                         float* __restrict__ out){
    __shared__ int sp[E_N];
    int tid = threadIdx.x;
    if (tid < E_N) sp[tid] = pidx[tid]*HOP_N;
    __syncthreads();
    int t = blockIdx.x*256 + tid;
    float acc = 0.f;
    #pragma unroll 4
    for (int e = 0; e < E_N; ++e) {
        int s = t + NSAMP - sp[e];
        if ((unsigned)s < (unsigned)NSAMP) {
            int f1 = s >> 8, n1 = s & 255;
            const float* base = wnd + ((size_t)(e*F_N + f1) << 9);
            acc += base[n1];
            if (f1 > 0) acc += base[n1 + 256 - 512];
        }
    }
    out[t] = acc;
}

// ---------------- launch ---------------------------------------------------
extern "C" void kernel_launch(void* const* d_in, const int* in_sizes, int n_in,
                              void* d_out, int out_size, void* d_ws, size_t ws_size,
                              hipStream_t stream) {
    const float* events  = (const float*)d_in[0];
    const float* times   = (const float*)d_in[1];
    const float* pos     = (const float*)d_in[2];
    const float* gen_pos = (const float*)d_in[3];
    const float* noise   = (const float*)d_in[4];
    const float* w_ee    = (const float*)d_in[5];
    const float* b_ee    = (const float*)d_in[6];
    const float* w_ep    = (const float*)d_in[7];
    const float* b_ep    = (const float*)d_in[8];
    const float* net_w   = (const float*)d_in[9];
    const float* net_b   = (const float*)d_in[10];
    const float* w_mag   = (const float*)d_in[11];
    const float* b_mag   = (const float*)d_in[12];
    const float* w_dith  = (const float*)d_in[13];
    const float* b_dith  = (const float*)d_in[14];
    float* out = (float*)d_out;

    // workspace layout (~181.5 MB, lifetime-based aliasing)
    char* ws8 = (char*)d_ws;
    unsigned short* xAh = (unsigned short*)(ws8);
    unsigned short* xAl = (unsigned short*)(ws8 + 33554432ull);
    unsigned short* xBh = (unsigned short*)(ws8 + 67108864ull);
    unsigned short* xBl = (unsigned short*)(ws8 + 100663296ull);
    float*          cs32= (float*)(ws8 + 67108864ull);            // 71303168 B
    unsigned short* csh = (unsigned short*)(ws8);                 // 35651584 B
    unsigned short* csl = (unsigned short*)(ws8 + 138412032ull);  // 35651584 B
    float*          bufB= (float*)(ws8 + 67108864ull);            // 64 MB
    char* sp = ws8 + 174063616ull;
    unsigned short* bash = (unsigned short*)sp;  sp += 557056;
    unsigned short* basl = (unsigned short*)sp;  sp += 557056;    // unused (layout kept)
    unsigned short* nwh  = (unsigned short*)sp;  sp += 2097152;
    unsigned short* nwl  = (unsigned short*)sp;  sp += 2097152;
    unsigned short* wmdh = (unsigned short*)sp;  sp += 655360;
    unsigned short* wmdl = (unsigned short*)sp;  sp += 655360;
    float* bmd   = (float*)sp;                   sp += 4096;
    float* e_buf = (float*)sp;                   sp += 262144;
    float* p_buf = (float*)sp;                   sp += 524288;
    int*   pidx  = (int*)sp;
    (void)basl;

    // independent prep
    k_basis_b1<<<(F2_N*KLD + 255)/256, 256, 0, stream>>>(bash);
    k_sim<<<E_N, 512, 0, stream>>>(times, pos, pidx);
    k_split4<<<1024, 256, 0, stream>>>((const float4*)net_w, nwh, nwl, 4*H_N*H_N/4);
    k_wmd<<<(WMD_N*H_N + 255)/256, 256, 0, stream>>>(w_mag, w_dith, b_mag, b_dith, wmdh, wmdl, bmd);
    k_eproj<<<(E_N*H_N)/256, 256, 0, stream>>>(events, w_ee, b_ee, e_buf);
    k_pproj<<<(F_N*H_N)/256, 256, 0, stream>>>(gen_pos, w_ep, b_ep, p_buf);
    k_xinit_bf<<<(M_ROWS*(H_N/4))/256, 256, 0, stream>>>(
        (const float4*)e_buf, (const float4*)p_buf, xAh, xAl);

    // 4 residual SELU layers (ping-pong, ends in xA pair)
    unsigned short *ih = xAh, *il = xAl, *oh = xBh, *ol = xBl;
    for (int i = 0; i < 4; ++i) {
        k_mfma_gemm<<<dim3(H_N/BN, M_ROWS/BM), 256, 0, stream>>>(
            ih, il, H_N, nwh + (size_t)i*H_N*H_N, nwl + (size_t)i*H_N*H_N, H_N,
            net_b + (size_t)i*H_N, oh, ol, nullptr, 0, H_N, 0, H_N);
        unsigned short* t;
        t = ih; ih = oh; oh = t;
        t = il; il = ol; ol = t;
    }
    // fused mag/dith (interleaved cols) -> cs32 fp32, |.| on even cols
    k_mfma_gemm<<<dim3(WMD_N/BN, M_ROWS/BM), 256, 0, stream>>>(
        ih, il, H_N, wmdh, wmdl, H_N, bmd, nullptr, nullptr, cs32, MDLD, H_N, 1, 2*C_N);

    // phase cumsum (k-chunked parallel scan) + sincos -> bf16 hi/lo iDFT operand
    k_phase<<<dim3(17, E_N), 256, 0, stream>>>(cs32, noise, csh, csl);

    // windowed = cs @ basis^T -> bufB fp32 [M][512]  (single-bf16 basis)
    k_mfma_gemm_b1<<<dim3(F2_N/BN, M_ROWS/BM), 256, 0, stream>>>(
        csh, csl, KLD, bash, KLD, bufB, W_N, KLD);

    // OLA + impulse-shift gather
    k_gather<<<NSAMP/256, 256, 0, stream>>>(bufB, pidx, out);
}